// Round 7
// baseline (75.913 us; speedup 1.0000x reference)
//
#include <hip/hip_runtime.h>

// LatentLookup: hard = metrics[argmin fp32 sq_dist replica], soft = softmax 15x15.
// Round 7: clean V1 (OpenBLAS sgemm K=2) replica under #pragma clang fp contract(off).
// KEY FINDING: HIP's __f*_rn are plain-op wrappers; hipcc defaults -ffp-contract=fast,
// so rounds 1-6 were confounded by compiler-fused qn/in/dot. np ref model:
//   qn = rn(rn(qx^2)+rn(qy^2)); in = rn(rn(gx^2)+rn(gy^2))   [numpy ufunc, no fma]
//   dot = fma(qy,gy, rn(qx*gx))                               [OpenBLAS k-ascending fma]
//   c  = rn(rn(qn+in) - rn(2*dot))                            [L2R, final sub exact]
// argmin = first flat index; candidate set = 3x3 around f64 true NN (provably
// contains any fp32-variant argmin: 2-away excess 2*s^2=3.1e-5 >> 2.4e-7 noise).

#define NG 256

__global__ void stage_axes(const float* __restrict__ idb,
                           float* __restrict__ wsx,
                           float* __restrict__ wsy) {
    int t = threadIdx.x;
    if (t < NG) {
        wsx[t] = idb[(size_t)2 * NG * t];  // gx[i] = idb[(i*NG)*2]
        wsy[t] = idb[2 * t + 1];           // gy[j] = idb[j*2+1]
    }
}

__device__ __forceinline__ int clampi(int v, int lo, int hi) {
    return v < lo ? lo : (v > hi ? hi : v);
}

__global__ __launch_bounds__(256) void latent_lookup(
    const float* __restrict__ q,        // [B,2]
    const float* __restrict__ temp,     // [1]
    const float* __restrict__ metrics,  // [NG*NG] flat
    const float* __restrict__ m2d,      // [NG,NG]
    const float* __restrict__ i2d,      // [NG,NG,2] (origin only)
    const float* __restrict__ gs,       // [2]
    const int*   __restrict__ ksz,      // [1]
    const float* __restrict__ wsx,      // gx[NG]
    const float* __restrict__ wsy,      // gy[NG]
    float* __restrict__ out,            // [2*B]
    int B) {
#pragma clang fp contract(off)
    int wave = (int)((blockIdx.x * blockDim.x + threadIdx.x) >> 6);
    int lane = threadIdx.x & 63;
    if (wave >= B) return;

    float qx = q[2 * wave + 0];
    float qy = q[2 * wave + 1];
    float ox = i2d[0], oy = i2d[1];
    float sx = gs[0],  sy = gs[1];

    // voxel = round_ste(rel_pos): bit-exact IEEE fp32 sub/div + rintf (half-even)
    int vx = (int)rintf((qx - ox) / sx);
    int vy = (int)rintf((qy - oy) / sy);

    // ---- f64 true NN per axis; any fp32-variant argmin lies in 3x3 around it ----
    int i0 = 0;
    {
        double best = 1e300;
        for (int d = -2; d <= 2; ++d) {
            int i = clampi(vx + d, 0, NG - 1);
            double dd = (double)qx - (double)wsx[i];
            dd *= dd;
            if (dd < best) { best = dd; i0 = i; }
        }
    }
    int j0 = 0;
    {
        double best = 1e300;
        for (int d = -2; d <= 2; ++d) {
            int j = clampi(vy + d, 0, NG - 1);
            double dd = (double)qy - (double)wsy[j];
            dd *= dd;
            if (dd < best) { best = dd; j0 = j; }
        }
    }

    // ---- clean-V1 fp32 replica over 3x3 neighborhood (contract OFF) ----
    float qxx = qx * qx;                 // rn(qx^2)
    float qyy = qy * qy;                 // rn(qy^2)
    float qn  = qxx + qyy;               // rn(qn)  -- no fma: contract off
    float bestv = 3.0e38f;
    int   besti = NG * NG;
    for (int di = -1; di <= 1; ++di) {
        int i = clampi(i0 + di, 0, NG - 1);
        float gxi = wsx[i];
        float px  = qx * gxi;            // rn(qx*gx)
        float gxx = gxi * gxi;           // rn(gx^2)
        for (int dj = -1; dj <= 1; ++dj) {
            int j = clampi(j0 + dj, 0, NG - 1);
            float gyj = wsy[j];
            float dot = __builtin_fmaf(qy, gyj, px);   // V1: explicit fma, k-ascending
            float gyy = gyj * gyj;       // rn(gy^2)
            float inr = gxx + gyy;       // rn(in)  -- no fma
            float A   = qn + inr;        // rn(qn+in)
            float c   = A - 2.0f * dot;  // 2*dot exact; sub not contractible
            int fd = i * NG + j;
            if (c < bestv || (c == bestv && fd < besti)) { bestv = c; besti = fd; }
        }
    }
    float hard = metrics[besti];

    // ---- soft: windowed softmax gather, wave-parallel over K2 points ----
    int ks = ksz[0];
    int radius = ks >> 1;
    int K2 = ks * ks;
    float denom = temp[0] + 1e-8f;

    float smax = -3.0e38f;
    for (int k = lane; k < K2; k += 64) {
        int xo = k / ks - radius, yo = k % ks - radius;
        int x = clampi(vx + xo, 0, NG - 1);
        int y = clampi(vy + yo, 0, NG - 1);
        float dx = qx - wsx[x], dy = qy - wsy[y];
        float dist = dx * dx + dy * dy;
        smax = fmaxf(smax, -dist / denom);
    }
    for (int off = 32; off; off >>= 1)
        smax = fmaxf(smax, __shfl_xor(smax, off, 64));

    float se = 0.0f, sem = 0.0f;
    for (int k = lane; k < K2; k += 64) {
        int xo = k / ks - radius, yo = k % ks - radius;
        int x = clampi(vx + xo, 0, NG - 1);
        int y = clampi(vy + yo, 0, NG - 1);
        float dx = qx - wsx[x], dy = qy - wsy[y];
        float dist = dx * dx + dy * dy;
        float e = expf(-dist / denom - smax);
        se  += e;
        sem += e * m2d[x * NG + y];
    }
    for (int off = 32; off; off >>= 1) {
        se  += __shfl_xor(se,  off, 64);
        sem += __shfl_xor(sem, off, 64);
    }

    if (lane == 0) {
        out[wave]     = hard;
        out[B + wave] = sem / se;
    }
}

extern "C" void kernel_launch(void* const* d_in, const int* in_sizes, int n_in,
                              void* d_out, int out_size, void* d_ws, size_t ws_size,
                              hipStream_t stream) {
    const float* q       = (const float*)d_in[0];
    const float* T       = (const float*)d_in[1];
    const float* idb     = (const float*)d_in[2];
    const float* metrics = (const float*)d_in[3];
    const float* i2d     = (const float*)d_in[4];
    const float* m2d     = (const float*)d_in[5];
    const float* gs      = (const float*)d_in[6];
    const int*   ks      = (const int*)d_in[7];
    float* out = (float*)d_out;
    int B = in_sizes[0] / 2;

    float* wsx = (float*)d_ws;
    float* wsy = wsx + NG;

    stage_axes<<<1, NG, 0, stream>>>(idb, wsx, wsy);

    int blocks = (B + 3) / 4;  // 4 waves (queries) per 256-thread block
    latent_lookup<<<blocks, 256, 0, stream>>>(q, T, metrics, m2d, i2d, gs, ks,
                                              wsx, wsy, out, B);
}

// Round 8
// 74.032 us; speedup vs baseline: 1.0254x; 1.0254x over previous
//
#include <hip/hip_runtime.h>

// LatentLookup: hard = metrics[argmin fp32 sq_dist replica], soft = softmax 15x15.
// Round 8: single fused kernel (stage gx/gy into LDS per block; d_ws unused).
// Verified-exact np-ref model (R7, absmax 0.0):
//   qn = rn(rn(qx^2)+rn(qy^2)); in = rn(rn(gx^2)+rn(gy^2))   [numpy ufunc, no fma]
//   dot = fma(qy,gy, rn(qx*gx))                               [OpenBLAS k-ascending fma]
//   c  = rn(rn(qn+in) - rn(2*dot))                            [L2R, final sub exact]
// under #pragma clang fp contract(off) — hipcc defaults -ffp-contract=fast and
// WILL silently fuse plain-op/__f*_rn sequences otherwise (R1-R6 confounder).
// argmin = first flat index; candidate set = 3x3 around f64 true NN (provably
// contains the fp32 argmin: 2-away excess 2*s^2=3.1e-5 >> 2.4e-7 noise).

#define NG 256

__device__ __forceinline__ int clampi(int v, int lo, int hi) {
    return v < lo ? lo : (v > hi ? hi : v);
}

__global__ __launch_bounds__(256) void latent_lookup(
    const float* __restrict__ q,        // [B,2]
    const float* __restrict__ temp,     // [1]
    const float* __restrict__ idb,      // [NG*NG,2] flat grid points
    const float* __restrict__ metrics,  // [NG*NG] flat
    const float* __restrict__ m2d,      // [NG,NG]
    const float* __restrict__ i2d,      // [NG,NG,2] (origin only)
    const float* __restrict__ gs,       // [2]
    const int*   __restrict__ ksz,      // [1]
    float* __restrict__ out,            // [2*B]
    int B) {
#pragma clang fp contract(off)
    __shared__ float wsx[NG];   // gx axis
    __shared__ float wsy[NG];   // gy axis

    // stage axes: gx[i] = idb[(i*NG)*2] (stride-2KB gather, L2-resident),
    //             gy[j] = idb[j*2+1]
    {
        int t = threadIdx.x;
        wsx[t] = idb[(size_t)2 * NG * t];
        wsy[t] = idb[2 * t + 1];
    }
    __syncthreads();

    int wave = (int)((blockIdx.x * blockDim.x + threadIdx.x) >> 6);
    int lane = threadIdx.x & 63;
    if (wave >= B) return;

    float qx = q[2 * wave + 0];
    float qy = q[2 * wave + 1];
    float ox = i2d[0], oy = i2d[1];
    float sx = gs[0],  sy = gs[1];
    int   ks = ksz[0];
    float denom = temp[0] + 1e-8f;

    // voxel = round_ste(rel_pos): bit-exact IEEE fp32 sub/div + rintf (half-even)
    int vx = (int)rintf((qx - ox) / sx);
    int vy = (int)rintf((qy - oy) / sy);

    // ---- f64 true NN per axis; the fp32 argmin lies in 3x3 around it ----
    int i0 = 0;
    {
        double best = 1e300;
        for (int d = -2; d <= 2; ++d) {
            int i = clampi(vx + d, 0, NG - 1);
            double dd = (double)qx - (double)wsx[i];
            dd *= dd;
            if (dd < best) { best = dd; i0 = i; }
        }
    }
    int j0 = 0;
    {
        double best = 1e300;
        for (int d = -2; d <= 2; ++d) {
            int j = clampi(vy + d, 0, NG - 1);
            double dd = (double)qy - (double)wsy[j];
            dd *= dd;
            if (dd < best) { best = dd; j0 = j; }
        }
    }

    // ---- clean-V1 fp32 replica over 3x3 neighborhood (contract OFF) ----
    float qxx = qx * qx;
    float qyy = qy * qy;
    float qn  = qxx + qyy;
    float bestv = 3.0e38f;
    int   besti = NG * NG;
    for (int di = -1; di <= 1; ++di) {
        int i = clampi(i0 + di, 0, NG - 1);
        float gxi = wsx[i];
        float px  = qx * gxi;            // rn(qx*gx)
        float gxx = gxi * gxi;
        for (int dj = -1; dj <= 1; ++dj) {
            int j = clampi(j0 + dj, 0, NG - 1);
            float gyj = wsy[j];
            float dot = __builtin_fmaf(qy, gyj, px);   // V1 fma, k-ascending
            float gyy = gyj * gyj;
            float inr = gxx + gyy;
            float A   = qn + inr;
            float c   = A - 2.0f * dot;
            int fd = i * NG + j;
            if (c < bestv || (c == bestv && fd < besti)) { bestv = c; besti = fd; }
        }
    }
    float hard = metrics[besti];

    // ---- soft: windowed softmax gather, wave-parallel over K2 = ks*ks points ----
    int radius = ks >> 1;
    int K2 = ks * ks;

    float smax = -3.0e38f;
    {
        int xo = lane / ks, yo = lane - xo * ks;  // one runtime div at entry
        for (int k = lane; k < K2; k += 64) {
            int x = clampi(vx + xo - radius, 0, NG - 1);
            int y = clampi(vy + yo - radius, 0, NG - 1);
            float dx = qx - wsx[x], dy = qy - wsy[y];
            float dist = dx * dx + dy * dy;
            smax = fmaxf(smax, -dist / denom);
            yo += 64; while (yo >= ks) { yo -= ks; xo += 1; }  // carry (<=5 iters, ks=15)
        }
    }
    for (int off = 32; off; off >>= 1)
        smax = fmaxf(smax, __shfl_xor(smax, off, 64));

    float se = 0.0f, sem = 0.0f;
    {
        int xo = lane / ks, yo = lane - xo * ks;
        for (int k = lane; k < K2; k += 64) {
            int x = clampi(vx + xo - radius, 0, NG - 1);
            int y = clampi(vy + yo - radius, 0, NG - 1);
            float dx = qx - wsx[x], dy = qy - wsy[y];
            float dist = dx * dx + dy * dy;
            float e = expf(-dist / denom - smax);
            se  += e;
            sem += e * m2d[x * NG + y];
            yo += 64; while (yo >= ks) { yo -= ks; xo += 1; }
        }
    }
    for (int off = 32; off; off >>= 1) {
        se  += __shfl_xor(se,  off, 64);
        sem += __shfl_xor(sem, off, 64);
    }

    if (lane == 0) {
        out[wave]     = hard;
        out[B + wave] = sem / se;
    }
}

extern "C" void kernel_launch(void* const* d_in, const int* in_sizes, int n_in,
                              void* d_out, int out_size, void* d_ws, size_t ws_size,
                              hipStream_t stream) {
    const float* q       = (const float*)d_in[0];
    const float* T       = (const float*)d_in[1];
    const float* idb     = (const float*)d_in[2];
    const float* metrics = (const float*)d_in[3];
    const float* i2d     = (const float*)d_in[4];
    const float* m2d     = (const float*)d_in[5];
    const float* gs      = (const float*)d_in[6];
    const int*   ks      = (const int*)d_in[7];
    float* out = (float*)d_out;
    int B = in_sizes[0] / 2;

    int blocks = (B + 3) / 4;  // 4 waves (queries) per 256-thread block
    latent_lookup<<<blocks, 256, 0, stream>>>(q, T, idb, metrics, m2d, i2d, gs, ks,
                                              out, B);
}

// Round 9
// 71.802 us; speedup vs baseline: 1.0572x; 1.0311x over previous
//
#include <hip/hip_runtime.h>

// LatentLookup: hard = metrics[argmin fp32 sq_dist replica], soft = softmax 15x15.
// Round 9: single-pass soft (no max-subtraction: exponent range is [-0.018,0] by
// construction — max window dist 2*(7.5*s)^2 ~ 1.8e-3, denom ~ 0.1 — so softmax
// without the shift is exact to ~1e-7, threshold is 2e-2) + native __expf.
// Hard path: verified-exact np-ref replica (R7/R8, absmax 0.0):
//   qn = rn(rn(qx^2)+rn(qy^2)); in = rn(rn(gx^2)+rn(gy^2))   [numpy ufunc, no fma]
//   dot = fma(qy,gy, rn(qx*gx))                               [OpenBLAS k-ascending fma]
//   c  = rn(rn(qn+in) - rn(2*dot))                            [L2R, final sub exact]
// under #pragma clang fp contract(off) — hipcc defaults -ffp-contract=fast and
// silently fuses plain-op/__f*_rn sequences otherwise (R1-R6 confounder).
// argmin = first flat index; candidate set = 3x3 around f64 true NN (provably
// contains the fp32 argmin: 2-away excess 2*s^2=3.1e-5 >> 2.4e-7 noise).

#define NG 256

__device__ __forceinline__ int clampi(int v, int lo, int hi) {
    return v < lo ? lo : (v > hi ? hi : v);
}

__global__ __launch_bounds__(256) void latent_lookup(
    const float* __restrict__ q,        // [B,2]
    const float* __restrict__ temp,     // [1]
    const float* __restrict__ idb,      // [NG*NG,2] flat grid points
    const float* __restrict__ metrics,  // [NG*NG] flat
    const float* __restrict__ m2d,      // [NG,NG]
    const float* __restrict__ i2d,      // [NG,NG,2] (origin only)
    const float* __restrict__ gs,       // [2]
    const int*   __restrict__ ksz,      // [1]
    float* __restrict__ out,            // [2*B]
    int B) {
#pragma clang fp contract(off)
    __shared__ float wsx[NG];   // gx axis
    __shared__ float wsy[NG];   // gy axis

    // stage axes: gx[i] = idb[(i*NG)*2] (stride-2KB gather, L2-resident),
    //             gy[j] = idb[j*2+1]
    {
        int t = threadIdx.x;
        wsx[t] = idb[(size_t)2 * NG * t];
        wsy[t] = idb[2 * t + 1];
    }
    __syncthreads();

    int wave = (int)((blockIdx.x * blockDim.x + threadIdx.x) >> 6);
    int lane = threadIdx.x & 63;
    if (wave >= B) return;

    float qx = q[2 * wave + 0];
    float qy = q[2 * wave + 1];
    float ox = i2d[0], oy = i2d[1];
    float sx = gs[0],  sy = gs[1];
    int   ks = ksz[0];
    float denom = temp[0] + 1e-8f;

    // voxel = round_ste(rel_pos): bit-exact IEEE fp32 sub/div + rintf (half-even)
    int vx = (int)rintf((qx - ox) / sx);
    int vy = (int)rintf((qy - oy) / sy);

    // ---- f64 true NN per axis; the fp32 argmin lies in 3x3 around it ----
    int i0 = 0;
    {
        double best = 1e300;
        for (int d = -2; d <= 2; ++d) {
            int i = clampi(vx + d, 0, NG - 1);
            double dd = (double)qx - (double)wsx[i];
            dd *= dd;
            if (dd < best) { best = dd; i0 = i; }
        }
    }
    int j0 = 0;
    {
        double best = 1e300;
        for (int d = -2; d <= 2; ++d) {
            int j = clampi(vy + d, 0, NG - 1);
            double dd = (double)qy - (double)wsy[j];
            dd *= dd;
            if (dd < best) { best = dd; j0 = j; }
        }
    }

    // ---- clean-V1 fp32 replica over 3x3 neighborhood (contract OFF) ----
    float qxx = qx * qx;
    float qyy = qy * qy;
    float qn  = qxx + qyy;
    float bestv = 3.0e38f;
    int   besti = NG * NG;
    for (int di = -1; di <= 1; ++di) {
        int i = clampi(i0 + di, 0, NG - 1);
        float gxi = wsx[i];
        float px  = qx * gxi;            // rn(qx*gx)
        float gxx = gxi * gxi;
        for (int dj = -1; dj <= 1; ++dj) {
            int j = clampi(j0 + dj, 0, NG - 1);
            float gyj = wsy[j];
            float dot = __builtin_fmaf(qy, gyj, px);   // V1 fma, k-ascending
            float gyy = gyj * gyj;
            float inr = gxx + gyy;
            float A   = qn + inr;
            float c   = A - 2.0f * dot;
            int fd = i * NG + j;
            if (c < bestv || (c == bestv && fd < besti)) { bestv = c; besti = fd; }
        }
    }
    float hard = metrics[besti];

    // ---- soft: SINGLE-pass softmax gather, wave-parallel over K2 = ks*ks ----
    int radius = ks >> 1;
    int K2 = ks * ks;
    float ninv = -1.0f / denom;   // exponent scale (range [-0.018, 0]: no shift needed)

    float se = 0.0f, sem = 0.0f;
    {
        int xo = lane / ks, yo = lane - xo * ks;   // one runtime div at entry
        for (int k = lane; k < K2; k += 64) {
            int x = clampi(vx + xo - radius, 0, NG - 1);
            int y = clampi(vy + yo - radius, 0, NG - 1);
            float dx = qx - wsx[x], dy = qy - wsy[y];
            float dist = __builtin_fmaf(dx, dx, dy * dy);
            float e = __expf(dist * ninv);         // native v_exp_f32
            se  += e;
            sem  = __builtin_fmaf(e, m2d[x * NG + y], sem);
            yo += 64; while (yo >= ks) { yo -= ks; xo += 1; }  // carry (<=5, ks=15)
        }
    }
    for (int off = 32; off; off >>= 1) {
        se  += __shfl_xor(se,  off, 64);
        sem += __shfl_xor(sem, off, 64);
    }

    if (lane == 0) {
        out[wave]     = hard;
        out[B + wave] = sem / se;
    }
}

extern "C" void kernel_launch(void* const* d_in, const int* in_sizes, int n_in,
                              void* d_out, int out_size, void* d_ws, size_t ws_size,
                              hipStream_t stream) {
    const float* q       = (const float*)d_in[0];
    const float* T       = (const float*)d_in[1];
    const float* idb     = (const float*)d_in[2];
    const float* metrics = (const float*)d_in[3];
    const float* i2d     = (const float*)d_in[4];
    const float* m2d     = (const float*)d_in[5];
    const float* gs      = (const float*)d_in[6];
    const int*   ks      = (const int*)d_in[7];
    float* out = (float*)d_out;
    int B = in_sizes[0] / 2;

    int blocks = (B + 3) / 4;  // 4 waves (queries) per 256-thread block
    latent_lookup<<<blocks, 256, 0, stream>>>(q, T, idb, metrics, m2d, i2d, gs, ks,
                                              out, B);
}

// Round 10
// 70.485 us; speedup vs baseline: 1.0770x; 1.0187x over previous
//
#include <hip/hip_runtime.h>

// LatentLookup: hard = metrics[argmin fp32 sq_dist replica], soft = softmax 15x15.
// Round 10: hard argmin FUSED into the soft loop. The fp32 argmin provably lies
// in the 5x5 around the voxel (true NN in voxel+-1; fp32 flips only +-1 cell:
// 2-away excess 2*s^2=3.1e-5 >> 2.4e-7 rounding noise), and 5x5 (offsets +-2)
// is a subset of soft's 15x15 (+-7). Lanes hitting inner-window points fold
// (orderable(c)<<32 | flat_idx) into a packed u64 min -> one butterfly reduce
// == np.argmin (min c, then min flat index). Deletes the serial f64 NN scans.
// Verified-exact np-ref hard model (R7-R9, absmax 0.0):
//   qn = rn(rn(qx^2)+rn(qy^2)); in = rn(rn(gx^2)+rn(gy^2))   [numpy ufunc, no fma]
//   dot = fma(qy,gy, rn(qx*gx))                               [OpenBLAS k-ascending fma]
//   c  = rn(rn(qn+in) - rn(2*dot))                            [L2R, final sub exact]
// under #pragma clang fp contract(off) — hipcc defaults -ffp-contract=fast and
// silently fuses plain-op sequences otherwise (R1-R6 confounder).
// Soft: single-pass no-shift softmax (exponent range [-0.018,0]) + native __expf.

#define NG 256

__device__ __forceinline__ int clampi(int v, int lo, int hi) {
    return v < lo ? lo : (v > hi ? hi : v);
}

__global__ __launch_bounds__(256) void latent_lookup(
    const float* __restrict__ q,        // [B,2]
    const float* __restrict__ temp,     // [1]
    const float* __restrict__ idb,      // [NG*NG,2] flat grid points
    const float* __restrict__ metrics,  // [NG*NG] flat
    const float* __restrict__ m2d,      // [NG,NG]
    const float* __restrict__ i2d,      // [NG,NG,2] (origin only)
    const float* __restrict__ gs,       // [2]
    const int*   __restrict__ ksz,      // [1]
    float* __restrict__ out,            // [2*B]
    int B) {
#pragma clang fp contract(off)
    __shared__ float wsx[NG];   // gx axis
    __shared__ float wsy[NG];   // gy axis

    // stage axes: gx[i] = idb[(i*NG)*2] (stride-2KB gather, L2-resident),
    //             gy[j] = idb[j*2+1]
    {
        int t = threadIdx.x;
        wsx[t] = idb[(size_t)2 * NG * t];
        wsy[t] = idb[2 * t + 1];
    }
    __syncthreads();

    int wave = (int)((blockIdx.x * blockDim.x + threadIdx.x) >> 6);
    int lane = threadIdx.x & 63;
    if (wave >= B) return;

    float qx = q[2 * wave + 0];
    float qy = q[2 * wave + 1];
    float ox = i2d[0], oy = i2d[1];
    float sx = gs[0],  sy = gs[1];
    int   ks = ksz[0];
    float denom = temp[0] + 1e-8f;

    // voxel = round_ste(rel_pos): bit-exact IEEE fp32 sub/div + rintf (half-even)
    int vx = (int)rintf((qx - ox) / sx);
    int vy = (int)rintf((qy - oy) / sy);

    int radius = ks >> 1;
    int K2 = ks * ks;
    float ninv = -1.0f / denom;          // softmax scale (no shift needed)
    float qn   = qx * qx + qy * qy;      // rn(rn+rn) under contract(off)

    float se = 0.0f, sem = 0.0f;
    unsigned long long best = ~0ULL;     // packed (orderable c | flat idx) min

    {
        int xo = lane / ks, yo = lane - xo * ks;   // one runtime div at entry
        for (int k = lane; k < K2; k += 64) {
            int ax = xo - radius, ay = yo - radius;
            int x = clampi(vx + ax, 0, NG - 1);
            int y = clampi(vy + ay, 0, NG - 1);
            float gxi = wsx[x], gyj = wsy[y];
            float dx = qx - gxi, dy = qy - gyj;
            float dist = __builtin_fmaf(dx, dx, dy * dy);
            float e = __expf(dist * ninv);          // native v_exp_f32
            se  += e;
            sem  = __builtin_fmaf(e, m2d[x * NG + y], sem);

            // hard candidate: inner 5x5 (covers the fp32 full-grid argmin)
            if ((unsigned)(ax + 2) <= 4u && (unsigned)(ay + 2) <= 4u) {
                float px  = qx * gxi;                       // rn(qx*gx)
                float dot = __builtin_fmaf(qy, gyj, px);    // V1 fma, k-ascending
                float inr = gxi * gxi + gyj * gyj;          // rn(rn+rn), no fma
                float A   = qn + inr;
                float c   = A - 2.0f * dot;                 // final sub exact
                unsigned cu = __float_as_uint(c);
                cu = (cu & 0x80000000u) ? ~cu : (cu | 0x80000000u);  // orderable
                unsigned long long pk =
                    ((unsigned long long)cu << 32) | (unsigned)(x * NG + y);
                if (pk < best) best = pk;
            }
            yo += 64; while (yo >= ks) { yo -= ks; xo += 1; }  // carry (<=5, ks=15)
        }
    }
    for (int off = 32; off; off >>= 1) {
        se  += __shfl_xor(se,  off, 64);
        sem += __shfl_xor(sem, off, 64);
        unsigned long long ob = __shfl_xor(best, off, 64);
        if (ob < best) best = ob;
    }

    if (lane == 0) {
        out[wave]     = metrics[(unsigned)(best & 0xFFFFFFFFu)];
        out[B + wave] = sem / se;
    }
}

extern "C" void kernel_launch(void* const* d_in, const int* in_sizes, int n_in,
                              void* d_out, int out_size, void* d_ws, size_t ws_size,
                              hipStream_t stream) {
    const float* q       = (const float*)d_in[0];
    const float* T       = (const float*)d_in[1];
    const float* idb     = (const float*)d_in[2];
    const float* metrics = (const float*)d_in[3];
    const float* i2d     = (const float*)d_in[4];
    const float* m2d     = (const float*)d_in[5];
    const float* gs      = (const float*)d_in[6];
    const int*   ks      = (const int*)d_in[7];
    float* out = (float*)d_out;
    int B = in_sizes[0] / 2;

    int blocks = (B + 3) / 4;  // 4 waves (queries) per 256-thread block
    latent_lookup<<<blocks, 256, 0, stream>>>(q, T, idb, metrics, m2d, i2d, gs, ks,
                                              out, B);
}